// Round 1
// baseline (3149.418 us; speedup 1.0000x reference)
//
#include <hip/hip_runtime.h>
#include <stdint.h>

#define S_LEN 1024
#define HDIM  4096
#define NHEAD 32
#define DHEAD 128
#define BATCH 2
#define MTOK  (BATCH * S_LEN)   // 2048

// -------- int8 dot4 helper (exact integer math) --------
__device__ __forceinline__ int dot4(int a, int b, int c) {
#if defined(__has_builtin)
#if __has_builtin(__builtin_amdgcn_sdot4)
  return __builtin_amdgcn_sdot4(a, b, c, false);
#else
  c += (int)(int8_t)(a)       * (int)(int8_t)(b);
  c += (int)(int8_t)(a >> 8)  * (int)(int8_t)(b >> 8);
  c += (int)(int8_t)(a >> 16) * (int)(int8_t)(b >> 16);
  c += (int)(int8_t)(a >> 24) * (int)(int8_t)(b >> 24);
  return c;
#endif
#else
  c += (int)(int8_t)(a)       * (int)(int8_t)(b);
  c += (int)(int8_t)(a >> 8)  * (int)(int8_t)(b >> 8);
  c += (int)(int8_t)(a >> 16) * (int)(int8_t)(b >> 16);
  c += (int)(int8_t)(a >> 24) * (int)(int8_t)(b >> 24);
  return c;
#endif
}

// -------- per-row symmetric fake-quant: x (row of 4096 f32) -> int8 + scale --------
// scale = max(absmax/qmax, 1e-8); q = clip(rint(x/scale), clipLo, qmax)
__global__ __launch_bounds__(256) void rowquant_kernel(
    const float* __restrict__ x, int8_t* __restrict__ q,
    float* __restrict__ scales, float qmax, float clipLo)
{
  const int row = blockIdx.x;
  const int t = threadIdx.x;
  const float* xr = x + (size_t)row * HDIM;
  float4 v[4];
  float am = 0.f;
#pragma unroll
  for (int i = 0; i < 4; ++i) {
    v[i] = ((const float4*)xr)[t + 256 * i];
    am = fmaxf(am, fmaxf(fmaxf(fabsf(v[i].x), fabsf(v[i].y)),
                         fmaxf(fabsf(v[i].z), fabsf(v[i].w))));
  }
#pragma unroll
  for (int off = 32; off > 0; off >>= 1) am = fmaxf(am, __shfl_down(am, off));
  __shared__ float wred[4];
  if ((t & 63) == 0) wred[t >> 6] = am;
  __syncthreads();
  const float m = fmaxf(fmaxf(wred[0], wred[1]), fmaxf(wred[2], wred[3]));
  const float scale = fmaxf(m / qmax, 1e-8f);
  if (t == 0) scales[row] = scale;
  int* qo = (int*)(q + (size_t)row * HDIM);
#pragma unroll
  for (int i = 0; i < 4; ++i) {
    int b0 = (int)fminf(fmaxf(rintf(v[i].x / scale), clipLo), qmax);
    int b1 = (int)fminf(fmaxf(rintf(v[i].y / scale), clipLo), qmax);
    int b2 = (int)fminf(fmaxf(rintf(v[i].z / scale), clipLo), qmax);
    int b3 = (int)fminf(fmaxf(rintf(v[i].w / scale), clipLo), qmax);
    qo[t + 256 * i] = (b0 & 0xff) | ((b1 & 0xff) << 8) | ((b2 & 0xff) << 16) | ((b3 & 0xff) << 24);
  }
}

// -------- int8 GEMM: C[m,n] = sa[m]*sb[n]*dot(A8[m,:4096], B8[n,:4096]) --------
// M=2048 (grid.y*128), N=4096 (grid.x*128), K=4096. 256 threads, 8x8 acc/thread.
__global__ __launch_bounds__(256) void gemm_i8_kernel(
    const int8_t* __restrict__ A, const float* __restrict__ sa,
    const int8_t* __restrict__ Bw, const float* __restrict__ sb,
    float* __restrict__ C)
{
  __shared__ int as[128][36];   // 32 dwords payload + pad to 36 (16B-aligned rows)
  __shared__ int bs[128][36];
  const int tid = threadIdx.x;
  const int tx = tid & 15, ty = tid >> 4;
  const int bm = blockIdx.y * 128, bn = blockIdx.x * 128;
  const int* A32 = (const int*)A + (size_t)bm * 1024;
  const int* B32 = (const int*)Bw + (size_t)bn * 1024;
  int acc[8][8];
#pragma unroll
  for (int i = 0; i < 8; ++i)
#pragma unroll
    for (int j = 0; j < 8; ++j) acc[i][j] = 0;

  for (int k0 = 0; k0 < 1024; k0 += 32) {   // 32 dwords = 128 int8 of K per step
#pragma unroll
    for (int i = 0; i < 4; ++i) {
      const int lin = tid + (i << 8);       // int4 unit: 1024 per tile
      const int r = lin >> 3;
      const int c4 = lin & 7;
      const int pc = ((c4 ^ ((r >> 3) & 7)) << 2);   // XOR swizzle, 16B granule
      const int4 va = *(const int4*)(A32 + (size_t)r * 1024 + k0 + (c4 << 2));
      const int4 vb = *(const int4*)(B32 + (size_t)r * 1024 + k0 + (c4 << 2));
      *(int4*)&as[r][pc] = va;
      *(int4*)&bs[r][pc] = vb;
    }
    __syncthreads();
#pragma unroll
    for (int g = 0; g < 8; ++g) {           // 8 groups of 4 dwords (16 int8) of K
      const int ca = ((g ^ (ty & 7)) << 2);
      const int cb = ((g ^ (tx & 7)) << 2);
      int4 av[8], bv[8];
#pragma unroll
      for (int i = 0; i < 8; ++i) av[i] = *(const int4*)&as[ty * 8 + i][ca];
#pragma unroll
      for (int j = 0; j < 8; ++j) bv[j] = *(const int4*)&bs[tx * 8 + j][cb];
#pragma unroll
      for (int i = 0; i < 8; ++i)
#pragma unroll
        for (int j = 0; j < 8; ++j) {
          int v2 = acc[i][j];
          v2 = dot4(av[i].x, bv[j].x, v2);
          v2 = dot4(av[i].y, bv[j].y, v2);
          v2 = dot4(av[i].z, bv[j].z, v2);
          v2 = dot4(av[i].w, bv[j].w, v2);
          acc[i][j] = v2;
        }
    }
    __syncthreads();
  }
  float sar[8], sbr[8];
#pragma unroll
  for (int i = 0; i < 8; ++i) sar[i] = sa[bm + ty * 8 + i];
#pragma unroll
  for (int j = 0; j < 8; ++j) sbr[j] = sb[bn + tx * 8 + j];
#pragma unroll
  for (int i = 0; i < 8; ++i) {
    float4 o0, o1;
    o0.x = sar[i] * sbr[0] * (float)acc[i][0];
    o0.y = sar[i] * sbr[1] * (float)acc[i][1];
    o0.z = sar[i] * sbr[2] * (float)acc[i][2];
    o0.w = sar[i] * sbr[3] * (float)acc[i][3];
    o1.x = sar[i] * sbr[4] * (float)acc[i][4];
    o1.y = sar[i] * sbr[5] * (float)acc[i][5];
    o1.z = sar[i] * sbr[6] * (float)acc[i][6];
    o1.w = sar[i] * sbr[7] * (float)acc[i][7];
    float* cp = C + (size_t)(bm + ty * 8 + i) * HDIM + bn + tx * 8;
    *(float4*)cp = o0;
    *(float4*)(cp + 4) = o1;
  }
}

// -------- RoPE (optional) + per-(b,s,h) 128-elem fake-quant8; out layout [b*NH+h][s][128] --------
// One wave per (token, head); lane d in 0..63 handles pair (d, d+64).
__global__ __launch_bounds__(256) void rope_quant_kernel(
    const float* __restrict__ y, int8_t* __restrict__ o8,
    float* __restrict__ oscale, int doRope)
{
  const int gw = (blockIdx.x * 256 + threadIdx.x) >> 6;  // 0..65535
  const int lane = threadIdx.x & 63;
  const int h = gw & (NHEAD - 1);
  const int tok = gw >> 5;                 // b*S+s
  const int s = tok & (S_LEN - 1);
  const float* yr = y + (size_t)tok * HDIM + h * DHEAD;
  float x0 = yr[lane], x1 = yr[lane + 64];
  float o0, o1;
  if (doRope) {
    const float e = (float)lane * (1.0f / 64.0f);
    const float inv = powf(10000.0f, -e);
    const float ang = (float)s * inv;
    float sn, c;
    sincosf(ang, &sn, &c);
    o0 = x0 * c - x1 * sn;     // rotate_half: d<64 gets -x_{d+64}*sin
    o1 = x1 * c + x0 * sn;     // d>=64 gets +x_{d-64}*sin (cos/sin tables repeat)
  } else {
    o0 = x0; o1 = x1;
  }
  float am = fmaxf(fabsf(o0), fabsf(o1));
#pragma unroll
  for (int off = 32; off > 0; off >>= 1) am = fmaxf(am, __shfl_xor(am, off));
  const float scale = fmaxf(am / 127.0f, 1e-8f);
  const float q0 = fminf(fmaxf(rintf(o0 / scale), -128.f), 127.f);
  const float q1 = fminf(fmaxf(rintf(o1 / scale), -128.f), 127.f);
  const size_t orow = (size_t)((tok >> 10) * NHEAD + h) * S_LEN + s;
  int8_t* op = o8 + orow * DHEAD;
  op[lane] = (int8_t)(int)q0;
  op[lane + 64] = (int8_t)(int)q1;
  if (lane == 0) oscale[orow] = scale;
}

// -------- attention: per block = (q row, b*h). int8 QK^T, fp32 softmax, p-quant, fp32 PV --------
__global__ __launch_bounds__(256) void attn_kernel(
    const int8_t* __restrict__ qq, const float* __restrict__ sq,
    const int8_t* __restrict__ kq, const float* __restrict__ sk,
    const int8_t* __restrict__ vq, const float* __restrict__ sv,
    float* __restrict__ attn)
{
  const int qi = blockIdx.x;
  const int bh = blockIdx.y;
  const int tid = threadIdx.x;
  const int nk = qi + 1;
  __shared__ float sc[S_LEN];
  __shared__ __align__(16) int qrow[32];
  __shared__ float red[4];
  __shared__ float ap[128];
  const size_t bhS = (size_t)bh * S_LEN;
  if (tid < 32) qrow[tid] = ((const int*)(qq + (bhS + qi) * DHEAD))[tid];
  __syncthreads();
  const float sqv = sq[bhS + qi];
  const int* k32 = (const int*)(kq + bhS * DHEAD);

  float lmax = -3.402823466e38f;
  for (int k = tid; k < nk; k += 256) {
    const int4* kr = (const int4*)(k32 + (size_t)k * 32);
    int acc = 0;
#pragma unroll
    for (int j = 0; j < 8; ++j) {
      const int4 kv = kr[j];
      const int4 qv = *(const int4*)&qrow[j * 4];
      acc = dot4(kv.x, qv.x, acc);
      acc = dot4(kv.y, qv.y, acc);
      acc = dot4(kv.z, qv.z, acc);
      acc = dot4(kv.w, qv.w, acc);
    }
    const float scf = ((float)acc * sqv * sk[bhS + k]) / sqrtf(128.0f);
    sc[k] = scf;
    lmax = fmaxf(lmax, scf);
  }
  // block max
#pragma unroll
  for (int off = 32; off > 0; off >>= 1) lmax = fmaxf(lmax, __shfl_down(lmax, off));
  if ((tid & 63) == 0) red[tid >> 6] = lmax;
  __syncthreads();
  const float gmax = fmaxf(fmaxf(red[0], red[1]), fmaxf(red[2], red[3]));
  __syncthreads();
  // exp + sum
  float lsum = 0.f;
  for (int k = tid; k < nk; k += 256) {
    const float e = expf(sc[k] - gmax);
    sc[k] = e;
    lsum += e;
  }
#pragma unroll
  for (int off = 32; off > 0; off >>= 1) lsum += __shfl_down(lsum, off);
  if ((tid & 63) == 0) red[tid >> 6] = lsum;
  __syncthreads();
  const float gsum = ((red[0] + red[1]) + red[2]) + red[3];
  // p fake-quant (scale = (1/sum)/127 since max p = exp(0)/sum), fold v-scale in
  const float pmax = 1.0f / gsum;
  const float pscale = fmaxf(pmax / 127.0f, 1e-8f);
  for (int k = tid; k < nk; k += 256) {
    const float pv = sc[k] / gsum;
    const float ci = fminf(fmaxf(rintf(pv / pscale), -128.0f), 127.0f);
    sc[k] = ci * pscale * sv[bhS + k];   // PV weight: pq_deq * sv[k]
  }
  __syncthreads();
  // PV: 2 halves of threads split k; 128 d-lanes each
  const int half = tid >> 7;
  const int d = tid & 127;
  const int8_t* vb = vq + bhS * DHEAD + d;
  float acc = 0.f;
  for (int k = half; k < nk; k += 2)
    acc += sc[k] * (float)vb[(size_t)k * DHEAD];
  if (half == 0) ap[d] = acc;
  __syncthreads();
  if (half == 1) {
    const int b = bh >> 5, h = bh & 31;
    attn[((size_t)(b * S_LEN + qi)) * HDIM + h * DHEAD + d] = ap[d] + acc;
  }
}

extern "C" void kernel_launch(void* const* d_in, const int* in_sizes, int n_in,
                              void* d_out, int out_size, void* d_ws, size_t ws_size,
                              hipStream_t stream) {
  const float* hs = (const float*)d_in[0];
  const float* wmat[4] = { (const float*)d_in[1], (const float*)d_in[2],
                           (const float*)d_in[3], (const float*)d_in[4] }; // wq,wk,wv,wo

  char* p = (char*)d_ws;
  auto take = [&](size_t sz) { char* r = p; p += (sz + 255) & ~(size_t)255; return r; };

  int8_t* xq8 = (int8_t*)take((size_t)MTOK * HDIM);            // 8.4 MB (reused for attnq)
  int8_t* w4[4];
  for (int i = 0; i < 4; ++i) w4[i] = (int8_t*)take((size_t)HDIM * HDIM);  // 4x16.8 MB
  float* sx = (float*)take((size_t)MTOK * 4);
  float* sw[4];
  for (int i = 0; i < 4; ++i) sw[i] = (float*)take((size_t)HDIM * 4);
  float* y = (float*)take((size_t)MTOK * HDIM * 4);            // 33.5 MB (reused for attn out)
  int8_t* qq8 = (int8_t*)take((size_t)MTOK * HDIM);
  int8_t* kq8 = (int8_t*)take((size_t)MTOK * HDIM);
  int8_t* vq8 = (int8_t*)take((size_t)MTOK * HDIM);
  float* sqs = (float*)take((size_t)BATCH * NHEAD * S_LEN * 4);
  float* sks = (float*)take((size_t)BATCH * NHEAD * S_LEN * 4);
  float* svs = (float*)take((size_t)BATCH * NHEAD * S_LEN * 4);
  float* sattn = (float*)take((size_t)MTOK * 4);

  // 1) quantize activations (8-bit) and weights (4-bit)
  rowquant_kernel<<<MTOK, 256, 0, stream>>>(hs, xq8, sx, 127.f, -128.f);
  for (int i = 0; i < 4; ++i)
    rowquant_kernel<<<HDIM, 256, 0, stream>>>(wmat[i], w4[i], sw[i], 7.f, -8.f);

  const dim3 gg(HDIM / 128, MTOK / 128);  // (32,16)
  // 2) Q
  gemm_i8_kernel<<<gg, 256, 0, stream>>>(xq8, sx, w4[0], sw[0], y);
  rope_quant_kernel<<<MTOK * NHEAD / 4, 256, 0, stream>>>(y, qq8, sqs, 1);
  // 3) K
  gemm_i8_kernel<<<gg, 256, 0, stream>>>(xq8, sx, w4[1], sw[1], y);
  rope_quant_kernel<<<MTOK * NHEAD / 4, 256, 0, stream>>>(y, kq8, sks, 1);
  // 4) V (no rope)
  gemm_i8_kernel<<<gg, 256, 0, stream>>>(xq8, sx, w4[2], sw[2], y);
  rope_quant_kernel<<<MTOK * NHEAD / 4, 256, 0, stream>>>(y, vq8, svs, 0);
  // 5) attention -> token-major attn matrix (reuse y)
  attn_kernel<<<dim3(S_LEN, BATCH * NHEAD), 256, 0, stream>>>(
      qq8, sqs, kq8, sks, vq8, svs, y);
  // 6) quantize attn rows (8-bit) -> reuse xq8
  rowquant_kernel<<<MTOK, 256, 0, stream>>>(y, xq8, sattn, 127.f, -128.f);
  // 7) output projection
  gemm_i8_kernel<<<gg, 256, 0, stream>>>(xq8, sattn, w4[3], sw[3], (float*)d_out);
}

// Round 2
// 1546.141 us; speedup vs baseline: 2.0370x; 2.0370x over previous
//
#include <hip/hip_runtime.h>
#include <stdint.h>

#define S_LEN 1024
#define HDIM  4096
#define NHEAD 32
#define DHEAD 128
#define BATCH 2
#define MTOK  (BATCH * S_LEN)   // 2048

typedef __attribute__((ext_vector_type(4))) int   i32x4;
typedef __attribute__((ext_vector_type(4))) float f32x4;
typedef __attribute__((ext_vector_type(8))) short bf16x8;

// -------- int8 dot4 helper (exact integer math) --------
__device__ __forceinline__ int dot4(int a, int b, int c) {
#if defined(__has_builtin)
#if __has_builtin(__builtin_amdgcn_sdot4)
  return __builtin_amdgcn_sdot4(a, b, c, false);
#else
  c += (int)(int8_t)(a)       * (int)(int8_t)(b);
  c += (int)(int8_t)(a >> 8)  * (int)(int8_t)(b >> 8);
  c += (int)(int8_t)(a >> 16) * (int)(int8_t)(b >> 16);
  c += (int)(int8_t)(a >> 24) * (int)(int8_t)(b >> 24);
  return c;
#endif
#else
  c += (int)(int8_t)(a)       * (int)(int8_t)(b);
  c += (int)(int8_t)(a >> 8)  * (int)(int8_t)(b >> 8);
  c += (int)(int8_t)(a >> 16) * (int)(int8_t)(b >> 16);
  c += (int)(int8_t)(a >> 24) * (int)(int8_t)(b >> 24);
  return c;
#endif
}

// float -> bf16 bits, round-to-nearest-even (exact for small ints)
__device__ __forceinline__ unsigned short f2bf(float f) {
  unsigned int u = __float_as_uint(f);
  unsigned int r = (u + 0x7fffu + ((u >> 16) & 1u)) >> 16;
  return (unsigned short)r;
}

// -------- per-row symmetric fake-quant: x (row of 4096 f32) -> int8 + scale --------
__global__ __launch_bounds__(256) void rowquant_kernel(
    const float* __restrict__ x, int8_t* __restrict__ q,
    float* __restrict__ scales, float qmax, float clipLo)
{
  const int row = blockIdx.x;
  const int t = threadIdx.x;
  const float* xr = x + (size_t)row * HDIM;
  float4 v[4];
  float am = 0.f;
#pragma unroll
  for (int i = 0; i < 4; ++i) {
    v[i] = ((const float4*)xr)[t + 256 * i];
    am = fmaxf(am, fmaxf(fmaxf(fabsf(v[i].x), fabsf(v[i].y)),
                         fmaxf(fabsf(v[i].z), fabsf(v[i].w))));
  }
#pragma unroll
  for (int off = 32; off > 0; off >>= 1) am = fmaxf(am, __shfl_down(am, off));
  __shared__ float wred[4];
  if ((t & 63) == 0) wred[t >> 6] = am;
  __syncthreads();
  const float m = fmaxf(fmaxf(wred[0], wred[1]), fmaxf(wred[2], wred[3]));
  const float scale = fmaxf(m / qmax, 1e-8f);
  if (t == 0) scales[row] = scale;
  int* qo = (int*)(q + (size_t)row * HDIM);
#pragma unroll
  for (int i = 0; i < 4; ++i) {
    int b0 = (int)fminf(fmaxf(rintf(v[i].x / scale), clipLo), qmax);
    int b1 = (int)fminf(fmaxf(rintf(v[i].y / scale), clipLo), qmax);
    int b2 = (int)fminf(fmaxf(rintf(v[i].z / scale), clipLo), qmax);
    int b3 = (int)fminf(fmaxf(rintf(v[i].w / scale), clipLo), qmax);
    qo[t + 256 * i] = (b0 & 0xff) | ((b1 & 0xff) << 8) | ((b2 & 0xff) << 16) | ((b3 & 0xff) << 24);
  }
}

// -------- int8 GEMM (dot4): C[m,n] = sa[m]*sb[n]*dot(A8[m,:],B8[n,:]) --------
__global__ __launch_bounds__(256) void gemm_i8_kernel(
    const int8_t* __restrict__ A, const float* __restrict__ sa,
    const int8_t* __restrict__ Bw, const float* __restrict__ sb,
    float* __restrict__ C)
{
  __shared__ int as[128][36];
  __shared__ int bs[128][36];
  const int tid = threadIdx.x;
  const int tx = tid & 15, ty = tid >> 4;
  const int bm = blockIdx.y * 128, bn = blockIdx.x * 128;
  const int* A32 = (const int*)A + (size_t)bm * 1024;
  const int* B32 = (const int*)Bw + (size_t)bn * 1024;
  int acc[8][8];
#pragma unroll
  for (int i = 0; i < 8; ++i)
#pragma unroll
    for (int j = 0; j < 8; ++j) acc[i][j] = 0;

  for (int k0 = 0; k0 < 1024; k0 += 32) {
#pragma unroll
    for (int i = 0; i < 4; ++i) {
      const int lin = tid + (i << 8);
      const int r = lin >> 3;
      const int c4 = lin & 7;
      const int pc = ((c4 ^ ((r >> 3) & 7)) << 2);
      const int4 va = *(const int4*)(A32 + (size_t)r * 1024 + k0 + (c4 << 2));
      const int4 vb = *(const int4*)(B32 + (size_t)r * 1024 + k0 + (c4 << 2));
      *(int4*)&as[r][pc] = va;
      *(int4*)&bs[r][pc] = vb;
    }
    __syncthreads();
#pragma unroll
    for (int g = 0; g < 8; ++g) {
      const int ca = ((g ^ (ty & 7)) << 2);
      const int cb = ((g ^ (tx & 7)) << 2);
      int4 av[8], bv[8];
#pragma unroll
      for (int i = 0; i < 8; ++i) av[i] = *(const int4*)&as[ty * 8 + i][ca];
#pragma unroll
      for (int j = 0; j < 8; ++j) bv[j] = *(const int4*)&bs[tx * 8 + j][cb];
#pragma unroll
      for (int i = 0; i < 8; ++i)
#pragma unroll
        for (int j = 0; j < 8; ++j) {
          int v2 = acc[i][j];
          v2 = dot4(av[i].x, bv[j].x, v2);
          v2 = dot4(av[i].y, bv[j].y, v2);
          v2 = dot4(av[i].z, bv[j].z, v2);
          v2 = dot4(av[i].w, bv[j].w, v2);
          acc[i][j] = v2;
        }
    }
    __syncthreads();
  }
  float sar[8], sbr[8];
#pragma unroll
  for (int i = 0; i < 8; ++i) sar[i] = sa[bm + ty * 8 + i];
#pragma unroll
  for (int j = 0; j < 8; ++j) sbr[j] = sb[bn + tx * 8 + j];
#pragma unroll
  for (int i = 0; i < 8; ++i) {
    float4 o0, o1;
    o0.x = sar[i] * sbr[0] * (float)acc[i][0];
    o0.y = sar[i] * sbr[1] * (float)acc[i][1];
    o0.z = sar[i] * sbr[2] * (float)acc[i][2];
    o0.w = sar[i] * sbr[3] * (float)acc[i][3];
    o1.x = sar[i] * sbr[4] * (float)acc[i][4];
    o1.y = sar[i] * sbr[5] * (float)acc[i][5];
    o1.z = sar[i] * sbr[6] * (float)acc[i][6];
    o1.w = sar[i] * sbr[7] * (float)acc[i][7];
    float* cp = C + (size_t)(bm + ty * 8 + i) * HDIM + bn + tx * 8;
    *(float4*)cp = o0;
    *(float4*)(cp + 4) = o1;
  }
}

// -------- RoPE + per-(b,s,h) fake-quant8 for Q,K; layout [bh][s][128] --------
__global__ __launch_bounds__(256) void rope_quant_kernel(
    const float* __restrict__ y, int8_t* __restrict__ o8,
    float* __restrict__ oscale, int doRope)
{
  const int gw = (blockIdx.x * 256 + threadIdx.x) >> 6;
  const int lane = threadIdx.x & 63;
  const int h = gw & (NHEAD - 1);
  const int tok = gw >> 5;
  const int s = tok & (S_LEN - 1);
  const float* yr = y + (size_t)tok * HDIM + h * DHEAD;
  float x0 = yr[lane], x1 = yr[lane + 64];
  float o0, o1;
  if (doRope) {
    const float e = (float)lane * (1.0f / 64.0f);
    const float inv = powf(10000.0f, -e);
    const float ang = (float)s * inv;
    float sn, c;
    sincosf(ang, &sn, &c);
    o0 = x0 * c - x1 * sn;
    o1 = x1 * c + x0 * sn;
  } else {
    o0 = x0; o1 = x1;
  }
  float am = fmaxf(fabsf(o0), fabsf(o1));
#pragma unroll
  for (int off = 32; off > 0; off >>= 1) am = fmaxf(am, __shfl_xor(am, off));
  const float scale = fmaxf(am / 127.0f, 1e-8f);
  const float q0 = fminf(fmaxf(rintf(o0 / scale), -128.f), 127.f);
  const float q1 = fminf(fmaxf(rintf(o1 / scale), -128.f), 127.f);
  const size_t orow = (size_t)((tok >> 10) * NHEAD + h) * S_LEN + s;
  int8_t* op = o8 + orow * DHEAD;
  op[lane] = (int8_t)(int)q0;
  op[lane + 64] = (int8_t)(int)q1;
  if (lane == 0) oscale[orow] = scale;
}

// -------- V: quant per (b,h,s) row + store TRANSPOSED [bh][d][s] --------
__global__ __launch_bounds__(256) void vtrans_kernel(
    const float* __restrict__ y, int8_t* __restrict__ vqT, float* __restrict__ sv)
{
  __shared__ int8_t vt[128][80];   // stride 80 for aligned b128 reads
  const int tid = threadIdx.x;
  const int wv = tid >> 6, lane = tid & 63;
  const int bh = blockIdx.y, s0 = blockIdx.x * 64;
  const int b = bh >> 5, h = bh & 31;
  for (int it = 0; it < 16; ++it) {
    const int tl = wv * 16 + it;
    const float* yr = y + ((size_t)(b * S_LEN + s0 + tl)) * HDIM + h * DHEAD;
    float x0 = yr[lane], x1 = yr[lane + 64];
    float am = fmaxf(fabsf(x0), fabsf(x1));
#pragma unroll
    for (int off = 32; off > 0; off >>= 1) am = fmaxf(am, __shfl_xor(am, off));
    const float scale = fmaxf(am / 127.0f, 1e-8f);
    const float q0 = fminf(fmaxf(rintf(x0 / scale), -128.f), 127.f);
    const float q1 = fminf(fmaxf(rintf(x1 / scale), -128.f), 127.f);
    vt[lane][tl] = (int8_t)(int)q0;
    vt[lane + 64][tl] = (int8_t)(int)q1;
    if (lane == 0) sv[(size_t)bh * S_LEN + s0 + tl] = scale;
  }
  __syncthreads();
  const int d = tid >> 1, half = tid & 1;
  i32x4 o0 = *(const i32x4*)(&vt[d][half * 32]);
  i32x4 o1 = *(const i32x4*)(&vt[d][half * 32 + 16]);
  int8_t* op = vqT + ((size_t)bh * 128 + d) * S_LEN + s0 + half * 32;
  *(i32x4*)op = o0;
  *(i32x4*)(op + 16) = o1;
}

// -------- MFMA flash attention: QB=64 q rows per block, two passes --------
#define QB 64
#define KB 64

__global__ __launch_bounds__(256) void attn_mfma_kernel(
    const int8_t* __restrict__ qq, const float* __restrict__ sq,
    const int8_t* __restrict__ kq, const float* __restrict__ sk,
    const int8_t* __restrict__ vqT, const float* __restrict__ sv,
    float* __restrict__ attn)
{
  __shared__ __align__(16) int8_t ks[KB][128];        // K tile, 16B-granule XOR swizzle
  __shared__ __align__(16) unsigned short vs[128][64]; // V^T tile bf16, 8-elem XOR swizzle
  __shared__ __align__(16) unsigned short ps[QB][64];  // P*sv bf16, 8-elem XOR swizzle
  __shared__ float sk_t[KB];
  __shared__ float sv_t[KB];

  const int tid = threadIdx.x;
  const int w = tid >> 6;        // wave 0..3 (owns q rows w*16..w*16+15)
  const int l = tid & 63;
  const int l15 = l & 15;
  const int lg = l >> 4;         // 0..3
  const int bx = blockIdx.x;
  const int bh = blockIdx.y;
  const int q0 = bx * QB;
  const size_t bhS = (size_t)bh * S_LEN;
  const int nkt = bx + 1;

  // Q fragments direct from global (A-frag row = l15)
  const int qrow = q0 + w * 16 + l15;
  const int8_t* qp = qq + (bhS + qrow) * (size_t)DHEAD;
  const i32x4 qa0 = *(const i32x4*)(qp + lg * 16);
  const i32x4 qa1 = *(const i32x4*)(qp + 64 + lg * 16);

  // per-lane scale*rsqrt(D) for the 4 C-rows this lane owns
  float sqv[4];
  int qg[4];
#pragma unroll
  for (int r = 0; r < 4; ++r) {
    qg[r] = q0 + w * 16 + lg * 4 + r;
    sqv[r] = sq[bhS + qg[r]] * 0.08838834764831843f;
  }

  float rmax[4] = {-3.0e38f, -3.0e38f, -3.0e38f, -3.0e38f};

  // ---------- pass 1: exact row max ----------
  for (int kt = 0; kt < nkt; ++kt) {
    const int k0 = kt * KB;
    {
      const int8_t* kgp = kq + (bhS + k0) * (size_t)DHEAD;
#pragma unroll
      for (int rr = 0; rr < 2; ++rr) {
        const int lin = tid + rr * 256;
        const int r = lin >> 3, g = lin & 7;
        const i32x4 v = *(const i32x4*)(kgp + (size_t)r * 128 + g * 16);
        *(i32x4*)(&ks[r][(g ^ (r & 7)) << 4]) = v;
      }
      if (tid < KB) sk_t[tid] = sk[bhS + k0 + tid];
    }
    __syncthreads();
    const bool diag = (kt == nkt - 1);
#pragma unroll
    for (int c = 0; c < 4; ++c) {
      const int krow = c * 16 + l15;
      const i32x4 b0 = *(const i32x4*)(&ks[krow][(lg ^ (krow & 7)) << 4]);
      const i32x4 b1 = *(const i32x4*)(&ks[krow][((lg + 4) ^ (krow & 7)) << 4]);
      i32x4 acc = {0, 0, 0, 0};
      acc = __builtin_amdgcn_mfma_i32_16x16x64_i8(qa0, b0, acc, 0, 0, 0);
      acc = __builtin_amdgcn_mfma_i32_16x16x64_i8(qa1, b1, acc, 0, 0, 0);
      const float skv = sk_t[krow];
      const int kgl = k0 + krow;
#pragma unroll
      for (int r = 0; r < 4; ++r) {
        const float s = (float)acc[r] * sqv[r] * skv;
        if (!diag || (kgl <= qg[r])) rmax[r] = fmaxf(rmax[r], s);
      }
    }
    __syncthreads();
  }
#pragma unroll
  for (int r = 0; r < 4; ++r)
#pragma unroll
    for (int off = 1; off < 16; off <<= 1)
      rmax[r] = fmaxf(rmax[r], __shfl_xor(rmax[r], off));

  // ---------- pass 2: P quant + PV ----------
  float rs[4] = {0.f, 0.f, 0.f, 0.f};
  f32x4 oacc[8];
#pragma unroll
  for (int ds = 0; ds < 8; ++ds) oacc[ds] = (f32x4){0.f, 0.f, 0.f, 0.f};

  const int qloc = w * 16 + l15;
  const int swA0 = (lg ^ (qloc & 7)) << 3;
  const int swA1 = ((lg + 4) ^ (qloc & 7)) << 3;

  for (int kt = 0; kt < nkt; ++kt) {
    const int k0 = kt * KB;
    {
      const int8_t* kgp = kq + (bhS + k0) * (size_t)DHEAD;
#pragma unroll
      for (int rr = 0; rr < 2; ++rr) {
        const int lin = tid + rr * 256;
        const int r = lin >> 3, g = lin & 7;
        const i32x4 v = *(const i32x4*)(kgp + (size_t)r * 128 + g * 16);
        *(i32x4*)(&ks[r][(g ^ (r & 7)) << 4]) = v;
      }
      const int8_t* vgp = vqT + ((size_t)bh * 128) * S_LEN + k0;
#pragma unroll
      for (int rr = 0; rr < 4; ++rr) {
        const int lin = tid + rr * 256;          // 8-byte granule: 128 rows x 8
        const int d = lin >> 3, g = lin & 7;
        const uint2 wv = *(const uint2*)(vgp + (size_t)d * S_LEN + g * 8);
        i32x4 out;
        out.x = (int)(f2bf((float)(int)(int8_t)(wv.x)) |
                      ((unsigned)f2bf((float)(int)(int8_t)(wv.x >> 8)) << 16));
        out.y = (int)(f2bf((float)(int)(int8_t)(wv.x >> 16)) |
                      ((unsigned)f2bf((float)(int)(int8_t)(wv.x >> 24)) << 16));
        out.z = (int)(f2bf((float)(int)(int8_t)(wv.y)) |
                      ((unsigned)f2bf((float)(int)(int8_t)(wv.y >> 8)) << 16));
        out.w = (int)(f2bf((float)(int)(int8_t)(wv.y >> 16)) |
                      ((unsigned)f2bf((float)(int)(int8_t)(wv.y >> 24)) << 16));
        *(i32x4*)(&vs[d][(g ^ (d & 7)) << 3]) = out;
      }
      if (tid < KB) { sk_t[tid] = sk[bhS + k0 + tid]; sv_t[tid] = sv[bhS + k0 + tid]; }
    }
    __syncthreads();
    const bool diag = (kt == nkt - 1);

    // QK^T + softmax-quant -> ps (wave-private rows)
#pragma unroll
    for (int c = 0; c < 4; ++c) {
      const int krow = c * 16 + l15;
      const i32x4 b0 = *(const i32x4*)(&ks[krow][(lg ^ (krow & 7)) << 4]);
      const i32x4 b1 = *(const i32x4*)(&ks[krow][((lg + 4) ^ (krow & 7)) << 4]);
      i32x4 acc = {0, 0, 0, 0};
      acc = __builtin_amdgcn_mfma_i32_16x16x64_i8(qa0, b0, acc, 0, 0, 0);
      acc = __builtin_amdgcn_mfma_i32_16x16x64_i8(qa1, b1, acc, 0, 0, 0);
      const float skv = sk_t[krow];
      const float svv = sv_t[krow];
      const int kgl = k0 + krow;
#pragma unroll
      for (int r = 0; r < 4; ++r) {
        const float s = (float)acc[r] * sqv[r] * skv;
        const bool valid = !diag || (kgl <= qg[r]);
        const float e = valid ? expf(s - rmax[r]) : 0.0f;
        rs[r] += e;
        const float pa = rintf(e * 127.0f) * svv;
        const int qr = w * 16 + lg * 4 + r;
        const int sidx = (((krow >> 3) ^ (qr & 7)) << 3) | (krow & 7);
        ps[qr][sidx] = f2bf(pa);
      }
    }

    // PV (A rows wave-private; vs staged block-wide, already synced)
    const bf16x8 a0 = *(const bf16x8*)&ps[qloc][swA0];
    const bf16x8 a1 = *(const bf16x8*)&ps[qloc][swA1];
#pragma unroll
    for (int ds = 0; ds < 8; ++ds) {
      const int d = ds * 16 + l15;
      const bf16x8 bv0 = *(const bf16x8*)&vs[d][(lg ^ (d & 7)) << 3];
      const bf16x8 bv1 = *(const bf16x8*)&vs[d][((lg + 4) ^ (d & 7)) << 3];
      oacc[ds] = __builtin_amdgcn_mfma_f32_16x16x32_bf16(a0, bv0, oacc[ds], 0, 0, 0);
      oacc[ds] = __builtin_amdgcn_mfma_f32_16x16x32_bf16(a1, bv1, oacc[ds], 0, 0, 0);
    }
    __syncthreads();
  }

  // ---------- epilogue ----------
#pragma unroll
  for (int r = 0; r < 4; ++r)
#pragma unroll
    for (int off = 1; off < 16; off <<= 1)
      rs[r] += __shfl_xor(rs[r], off);

  const int b = bh >> 5, h = bh & 31;
#pragma unroll
  for (int r = 0; r < 4; ++r) {
    const float inv = 1.0f / (127.0f * rs[r]);
    float* op = attn + ((size_t)(b * S_LEN + qg[r])) * HDIM + h * DHEAD + l15;
#pragma unroll
    for (int ds = 0; ds < 8; ++ds)
      op[ds * 16] = oacc[ds][r] * inv;
  }
}

extern "C" void kernel_launch(void* const* d_in, const int* in_sizes, int n_in,
                              void* d_out, int out_size, void* d_ws, size_t ws_size,
                              hipStream_t stream) {
  const float* hs = (const float*)d_in[0];
  const float* wmat[4] = { (const float*)d_in[1], (const float*)d_in[2],
                           (const float*)d_in[3], (const float*)d_in[4] };

  char* p = (char*)d_ws;
  auto take = [&](size_t sz) { char* r = p; p += (sz + 255) & ~(size_t)255; return r; };

  int8_t* xq8 = (int8_t*)take((size_t)MTOK * HDIM);
  int8_t* w4[4];
  for (int i = 0; i < 4; ++i) w4[i] = (int8_t*)take((size_t)HDIM * HDIM);
  float* sx = (float*)take((size_t)MTOK * 4);
  float* sw[4];
  for (int i = 0; i < 4; ++i) sw[i] = (float*)take((size_t)HDIM * 4);
  float* y = (float*)take((size_t)MTOK * HDIM * 4);
  int8_t* qq8 = (int8_t*)take((size_t)MTOK * HDIM);
  int8_t* kq8 = (int8_t*)take((size_t)MTOK * HDIM);
  int8_t* vqT = (int8_t*)take((size_t)MTOK * HDIM);
  float* sqs = (float*)take((size_t)BATCH * NHEAD * S_LEN * 4);
  float* sks = (float*)take((size_t)BATCH * NHEAD * S_LEN * 4);
  float* svs = (float*)take((size_t)BATCH * NHEAD * S_LEN * 4);
  float* sattn = (float*)take((size_t)MTOK * 4);

  rowquant_kernel<<<MTOK, 256, 0, stream>>>(hs, xq8, sx, 127.f, -128.f);
  for (int i = 0; i < 4; ++i)
    rowquant_kernel<<<HDIM, 256, 0, stream>>>(wmat[i], w4[i], sw[i], 7.f, -8.f);

  const dim3 gg(HDIM / 128, MTOK / 128);
  gemm_i8_kernel<<<gg, 256, 0, stream>>>(xq8, sx, w4[0], sw[0], y);
  rope_quant_kernel<<<MTOK * NHEAD / 4, 256, 0, stream>>>(y, qq8, sqs, 1);
  gemm_i8_kernel<<<gg, 256, 0, stream>>>(xq8, sx, w4[1], sw[1], y);
  rope_quant_kernel<<<MTOK * NHEAD / 4, 256, 0, stream>>>(y, kq8, sks, 1);
  gemm_i8_kernel<<<gg, 256, 0, stream>>>(xq8, sx, w4[2], sw[2], y);
  vtrans_kernel<<<dim3(S_LEN / 64, BATCH * NHEAD), 256, 0, stream>>>(y, vqT, svs);

  attn_mfma_kernel<<<dim3(S_LEN / QB, BATCH * NHEAD), 256, 0, stream>>>(
      qq8, sqs, kq8, sks, vqT, svs, y);

  rowquant_kernel<<<MTOK, 256, 0, stream>>>(y, xq8, sattn, 127.f, -128.f);
  gemm_i8_kernel<<<gg, 256, 0, stream>>>(xq8, sattn, w4[3], sw[3], (float*)d_out);
}

// Round 3
// 494.918 us; speedup vs baseline: 6.3635x; 3.1240x over previous
//
#include <hip/hip_runtime.h>
#include <stdint.h>

#define S_LEN 1024
#define HDIM  4096
#define NHEAD 32
#define DHEAD 128
#define BATCH 2
#define MTOK  (BATCH * S_LEN)   // 2048

typedef __attribute__((ext_vector_type(4))) int   i32x4;
typedef __attribute__((ext_vector_type(4))) float f32x4;
typedef __attribute__((ext_vector_type(8))) short bf16x8;

#define GLOBAL_AS __attribute__((address_space(1)))
#define LDS_AS    __attribute__((address_space(3)))

__device__ __forceinline__ void gl2lds16(const void* g, void* l) {
  __builtin_amdgcn_global_load_lds((const GLOBAL_AS unsigned int*)(g),
                                   (LDS_AS unsigned int*)(l), 16, 0, 0);
}

// float -> bf16 bits, round-to-nearest-even (exact for small ints)
__device__ __forceinline__ unsigned short f2bf(float f) {
  unsigned int u = __float_as_uint(f);
  unsigned int r = (u + 0x7fffu + ((u >> 16) & 1u)) >> 16;
  return (unsigned short)r;
}

// -------- per-row symmetric fake-quant: x (row of 4096 f32) -> int8 + scale --------
__global__ __launch_bounds__(256) void rowquant_kernel(
    const float* __restrict__ x, int8_t* __restrict__ q,
    float* __restrict__ scales, float qmax, float clipLo)
{
  const int row = blockIdx.x;
  const int t = threadIdx.x;
  const float* xr = x + (size_t)row * HDIM;
  float4 v[4];
  float am = 0.f;
#pragma unroll
  for (int i = 0; i < 4; ++i) {
    v[i] = ((const float4*)xr)[t + 256 * i];
    am = fmaxf(am, fmaxf(fmaxf(fabsf(v[i].x), fabsf(v[i].y)),
                         fmaxf(fabsf(v[i].z), fabsf(v[i].w))));
  }
#pragma unroll
  for (int off = 32; off > 0; off >>= 1) am = fmaxf(am, __shfl_down(am, off));
  __shared__ float wred[4];
  if ((t & 63) == 0) wred[t >> 6] = am;
  __syncthreads();
  const float m = fmaxf(fmaxf(wred[0], wred[1]), fmaxf(wred[2], wred[3]));
  const float scale = fmaxf(m / qmax, 1e-8f);
  if (t == 0) scales[row] = scale;
  int* qo = (int*)(q + (size_t)row * HDIM);
#pragma unroll
  for (int i = 0; i < 4; ++i) {
    int b0 = (int)fminf(fmaxf(rintf(v[i].x / scale), clipLo), qmax);
    int b1 = (int)fminf(fmaxf(rintf(v[i].y / scale), clipLo), qmax);
    int b2 = (int)fminf(fmaxf(rintf(v[i].z / scale), clipLo), qmax);
    int b3 = (int)fminf(fmaxf(rintf(v[i].w / scale), clipLo), qmax);
    qo[t + 256 * i] = (b0 & 0xff) | ((b1 & 0xff) << 8) | ((b2 & 0xff) << 16) | ((b3 & 0xff) << 24);
  }
}

// -------- i8 MFMA GEMM: C[m,n] = sa[m]*sb[n]*dot(A8[m,:4096], B8[n,:4096]) --------
// 128x128 tile, BK=128 bytes, 4 waves each computing 64x64.
// Staging: global_load_lds width16, linear LDS dest, pre-swizzled global src
// (slot^row XOR), fragment reads apply the same XOR -> ~conflict-free.
__global__ __launch_bounds__(256) void gemm_i8_mfma_kernel(
    const int8_t* __restrict__ A, const float* __restrict__ sa,
    const int8_t* __restrict__ Bw, const float* __restrict__ sb,
    float* __restrict__ C)
{
  __shared__ __align__(16) int8_t asB[128 * 128];
  __shared__ __align__(16) int8_t bsB[128 * 128];

  // XCD-chunked bijective swizzle over 512 blocks (64 per XCD)
  const int flat = blockIdx.y * gridDim.x + blockIdx.x;
  const int nf = (flat & 7) * 64 + (flat >> 3);
  const int bx = nf & 31, by = nf >> 5;
  const int bm = by * 128, bn = bx * 128;

  const int tid = threadIdx.x;
  const int w = tid >> 6, l = tid & 63;
  const int l15 = l & 15, lg = l >> 4, l7 = l & 7;
  const int m0 = (w >> 1) * 64, n0 = (w & 1) * 64;

  // staging source (per-lane): row-in-8 = l>>3, slot = (l&7)^(l>>3)
  const int lr = l >> 3;
  const int srcSlot = (l & 7) ^ lr;
  const int8_t* aRow = A + (size_t)(bm + lr) * HDIM + srcSlot * 16;
  const int8_t* bRow = Bw + (size_t)(bn + lr) * HDIM + srcSlot * 16;

  i32x4 acc[4][4];
#pragma unroll
  for (int i = 0; i < 4; ++i)
#pragma unroll
    for (int j = 0; j < 4; ++j) acc[i][j] = (i32x4){0, 0, 0, 0};

  for (int k0 = 0; k0 < HDIM; k0 += 128) {
#pragma unroll
    for (int i = 0; i < 4; ++i) {
      const int r0 = w * 32 + i * 8;               // wave-uniform
      gl2lds16(aRow + (size_t)r0 * HDIM + k0, asB + r0 * 128);
      gl2lds16(bRow + (size_t)r0 * HDIM + k0, bsB + r0 * 128);
    }
    __syncthreads();
#pragma unroll
    for (int kk = 0; kk < 2; ++kk) {
      i32x4 aF[4], bF[4];
      const int slot = (((kk << 2) + lg) ^ l7) << 4;
#pragma unroll
      for (int i = 0; i < 4; ++i)
        aF[i] = *(const i32x4*)(asB + (m0 + i * 16 + l15) * 128 + slot);
#pragma unroll
      for (int j = 0; j < 4; ++j)
        bF[j] = *(const i32x4*)(bsB + (n0 + j * 16 + l15) * 128 + slot);
#pragma unroll
      for (int i = 0; i < 4; ++i)
#pragma unroll
        for (int j = 0; j < 4; ++j)
          acc[i][j] = __builtin_amdgcn_mfma_i32_16x16x64_i8(aF[i], bF[j], acc[i][j], 0, 0, 0);
    }
    __syncthreads();
  }

  // epilogue: C row = bm+m0+i*16+lg*4+r, col = bn+n0+j*16+l15
  float sbr[4];
#pragma unroll
  for (int j = 0; j < 4; ++j) sbr[j] = sb[bn + n0 + j * 16 + l15];
#pragma unroll
  for (int i = 0; i < 4; ++i) {
#pragma unroll
    for (int r = 0; r < 4; ++r) {
      const int m = bm + m0 + i * 16 + lg * 4 + r;
      const float sm = sa[m];
      float* cp = C + (size_t)m * HDIM + bn + n0 + l15;
#pragma unroll
      for (int j = 0; j < 4; ++j)
        cp[j * 16] = sm * sbr[j] * (float)acc[i][j][r];
    }
  }
}

// -------- RoPE + per-(b,s,h) fake-quant8 for Q,K; layout [bh][s][128] --------
__global__ __launch_bounds__(256) void rope_quant_kernel(
    const float* __restrict__ y, int8_t* __restrict__ o8,
    float* __restrict__ oscale, int doRope)
{
  const int gw = (blockIdx.x * 256 + threadIdx.x) >> 6;
  const int lane = threadIdx.x & 63;
  const int h = gw & (NHEAD - 1);
  const int tok = gw >> 5;
  const int s = tok & (S_LEN - 1);
  const float* yr = y + (size_t)tok * HDIM + h * DHEAD;
  float x0 = yr[lane], x1 = yr[lane + 64];
  float o0, o1;
  if (doRope) {
    const float e = (float)lane * (1.0f / 64.0f);
    const float inv = powf(10000.0f, -e);
    const float ang = (float)s * inv;
    float sn, c;
    sincosf(ang, &sn, &c);
    o0 = x0 * c - x1 * sn;
    o1 = x1 * c + x0 * sn;
  } else {
    o0 = x0; o1 = x1;
  }
  float am = fmaxf(fabsf(o0), fabsf(o1));
#pragma unroll
  for (int off = 32; off > 0; off >>= 1) am = fmaxf(am, __shfl_xor(am, off));
  const float scale = fmaxf(am / 127.0f, 1e-8f);
  const float q0 = fminf(fmaxf(rintf(o0 / scale), -128.f), 127.f);
  const float q1 = fminf(fmaxf(rintf(o1 / scale), -128.f), 127.f);
  const size_t orow = (size_t)((tok >> 10) * NHEAD + h) * S_LEN + s;
  int8_t* op = o8 + orow * DHEAD;
  op[lane] = (int8_t)(int)q0;
  op[lane + 64] = (int8_t)(int)q1;
  if (lane == 0) oscale[orow] = scale;
}

// -------- V: quant per (b,h,s) row + store TRANSPOSED [bh][d][s] --------
__global__ __launch_bounds__(256) void vtrans_kernel(
    const float* __restrict__ y, int8_t* __restrict__ vqT, float* __restrict__ sv)
{
  __shared__ int8_t vt[128][80];
  const int tid = threadIdx.x;
  const int wv = tid >> 6, lane = tid & 63;
  const int bh = blockIdx.y, s0 = blockIdx.x * 64;
  const int b = bh >> 5, h = bh & 31;
  for (int it = 0; it < 16; ++it) {
    const int tl = wv * 16 + it;
    const float* yr = y + ((size_t)(b * S_LEN + s0 + tl)) * HDIM + h * DHEAD;
    float x0 = yr[lane], x1 = yr[lane + 64];
    float am = fmaxf(fabsf(x0), fabsf(x1));
#pragma unroll
    for (int off = 32; off > 0; off >>= 1) am = fmaxf(am, __shfl_xor(am, off));
    const float scale = fmaxf(am / 127.0f, 1e-8f);
    const float q0 = fminf(fmaxf(rintf(x0 / scale), -128.f), 127.f);
    const float q1 = fminf(fmaxf(rintf(x1 / scale), -128.f), 127.f);
    vt[lane][tl] = (int8_t)(int)q0;
    vt[lane + 64][tl] = (int8_t)(int)q1;
    if (lane == 0) sv[(size_t)bh * S_LEN + s0 + tl] = scale;
  }
  __syncthreads();
  const int d = tid >> 1, half = tid & 1;
  i32x4 o0 = *(const i32x4*)(&vt[d][half * 32]);
  i32x4 o1 = *(const i32x4*)(&vt[d][half * 32 + 16]);
  int8_t* op = vqT + ((size_t)bh * 128 + d) * S_LEN + s0 + half * 32;
  *(i32x4*)op = o0;
  *(i32x4*)(op + 16) = o1;
}

// -------- MFMA flash attention: QB=64 q rows per block, two passes --------
#define QB 64
#define KB 64

__global__ __launch_bounds__(256) void attn_mfma_kernel(
    const int8_t* __restrict__ qq, const float* __restrict__ sq,
    const int8_t* __restrict__ kq, const float* __restrict__ sk,
    const int8_t* __restrict__ vqT, const float* __restrict__ sv,
    float* __restrict__ attn)
{
  __shared__ __align__(16) int8_t ks[KB][128];
  __shared__ __align__(16) unsigned short vs[128][64];
  __shared__ __align__(16) unsigned short ps[QB][64];
  __shared__ float sk_t[KB];
  __shared__ float sv_t[KB];

  const int tid = threadIdx.x;
  const int w = tid >> 6;
  const int l = tid & 63;
  const int l15 = l & 15;
  const int lg = l >> 4;
  const int bx = blockIdx.x;
  const int bh = blockIdx.y;
  const int q0 = bx * QB;
  const size_t bhS = (size_t)bh * S_LEN;
  const int nkt = bx + 1;

  const int qrow = q0 + w * 16 + l15;
  const int8_t* qp = qq + (bhS + qrow) * (size_t)DHEAD;
  const i32x4 qa0 = *(const i32x4*)(qp + lg * 16);
  const i32x4 qa1 = *(const i32x4*)(qp + 64 + lg * 16);

  float sqv[4];
  int qg[4];
#pragma unroll
  for (int r = 0; r < 4; ++r) {
    qg[r] = q0 + w * 16 + lg * 4 + r;
    sqv[r] = sq[bhS + qg[r]] * 0.08838834764831843f;
  }

  float rmax[4] = {-3.0e38f, -3.0e38f, -3.0e38f, -3.0e38f};

  // ---------- pass 1: exact row max ----------
  for (int kt = 0; kt < nkt; ++kt) {
    const int k0 = kt * KB;
    {
      const int8_t* kgp = kq + (bhS + k0) * (size_t)DHEAD;
#pragma unroll
      for (int rr = 0; rr < 2; ++rr) {
        const int lin = tid + rr * 256;
        const int r = lin >> 3, g = lin & 7;
        const i32x4 v = *(const i32x4*)(kgp + (size_t)r * 128 + g * 16);
        *(i32x4*)(&ks[r][(g ^ (r & 7)) << 4]) = v;
      }
      if (tid < KB) sk_t[tid] = sk[bhS + k0 + tid];
    }
    __syncthreads();
    const bool diag = (kt == nkt - 1);
#pragma unroll
    for (int c = 0; c < 4; ++c) {
      const int krow = c * 16 + l15;
      const i32x4 b0 = *(const i32x4*)(&ks[krow][(lg ^ (krow & 7)) << 4]);
      const i32x4 b1 = *(const i32x4*)(&ks[krow][((lg + 4) ^ (krow & 7)) << 4]);
      i32x4 acc = {0, 0, 0, 0};
      acc = __builtin_amdgcn_mfma_i32_16x16x64_i8(qa0, b0, acc, 0, 0, 0);
      acc = __builtin_amdgcn_mfma_i32_16x16x64_i8(qa1, b1, acc, 0, 0, 0);
      const float skv = sk_t[krow];
      const int kgl = k0 + krow;
#pragma unroll
      for (int r = 0; r < 4; ++r) {
        const float s = (float)acc[r] * sqv[r] * skv;
        if (!diag || (kgl <= qg[r])) rmax[r] = fmaxf(rmax[r], s);
      }
    }
    __syncthreads();
  }
#pragma unroll
  for (int r = 0; r < 4; ++r)
#pragma unroll
    for (int off = 1; off < 16; off <<= 1)
      rmax[r] = fmaxf(rmax[r], __shfl_xor(rmax[r], off));

  // ---------- pass 2: P quant + PV ----------
  float rs[4] = {0.f, 0.f, 0.f, 0.f};
  f32x4 oacc[8];
#pragma unroll
  for (int ds = 0; ds < 8; ++ds) oacc[ds] = (f32x4){0.f, 0.f, 0.f, 0.f};

  const int qloc = w * 16 + l15;
  const int swA0 = (lg ^ (qloc & 7)) << 3;
  const int swA1 = ((lg + 4) ^ (qloc & 7)) << 3;

  for (int kt = 0; kt < nkt; ++kt) {
    const int k0 = kt * KB;
    {
      const int8_t* kgp = kq + (bhS + k0) * (size_t)DHEAD;
#pragma unroll
      for (int rr = 0; rr < 2; ++rr) {
        const int lin = tid + rr * 256;
        const int r = lin >> 3, g = lin & 7;
        const i32x4 v = *(const i32x4*)(kgp + (size_t)r * 128 + g * 16);
        *(i32x4*)(&ks[r][(g ^ (r & 7)) << 4]) = v;
      }
      const int8_t* vgp = vqT + ((size_t)bh * 128) * S_LEN + k0;
#pragma unroll
      for (int rr = 0; rr < 4; ++rr) {
        const int lin = tid + rr * 256;
        const int d = lin >> 3, g = lin & 7;
        const uint2 wv = *(const uint2*)(vgp + (size_t)d * S_LEN + g * 8);
        i32x4 out;
        out.x = (int)(f2bf((float)(int)(int8_t)(wv.x)) |
                      ((unsigned)f2bf((float)(int)(int8_t)(wv.x >> 8)) << 16));
        out.y = (int)(f2bf((float)(int)(int8_t)(wv.x >> 16)) |
                      ((unsigned)f2bf((float)(int)(int8_t)(wv.x >> 24)) << 16));
        out.z = (int)(f2bf((float)(int)(int8_t)(wv.y)) |
                      ((unsigned)f2bf((float)(int)(int8_t)(wv.y >> 8)) << 16));
        out.w = (int)(f2bf((float)(int)(int8_t)(wv.y >> 16)) |
                      ((unsigned)f2bf((float)(int)(int8_t)(wv.y >> 24)) << 16));
        *(i32x4*)(&vs[d][(g ^ (d & 7)) << 3]) = out;
      }
      if (tid < KB) { sk_t[tid] = sk[bhS + k0 + tid]; sv_t[tid] = sv[bhS + k0 + tid]; }
    }
    __syncthreads();
    const bool diag = (kt == nkt - 1);

#pragma unroll
    for (int c = 0; c < 4; ++c) {
      const int krow = c * 16 + l15;
      const i32x4 b0 = *(const i32x4*)(&ks[krow][(lg ^ (krow & 7)) << 4]);
      const i32x4 b1 = *(const i32x4*)(&ks[krow][((lg + 4) ^ (krow & 7)) << 4]);
      i32x4 acc = {0, 0, 0, 0};
      acc = __builtin_amdgcn_mfma_i32_16x16x64_i8(qa0, b0, acc, 0, 0, 0);
      acc = __builtin_amdgcn_mfma_i32_16x16x64_i8(qa1, b1, acc, 0, 0, 0);
      const float skv = sk_t[krow];
      const float svv = sv_t[krow];
      const int kgl = k0 + krow;
#pragma unroll
      for (int r = 0; r < 4; ++r) {
        const float s = (float)acc[r] * sqv[r] * skv;
        const bool valid = !diag || (kgl <= qg[r]);
        const float e = valid ? expf(s - rmax[r]) : 0.0f;
        rs[r] += e;
        const float pa = rintf(e * 127.0f) * svv;
        const int qr = w * 16 + lg * 4 + r;
        const int sidx = (((krow >> 3) ^ (qr & 7)) << 3) | (krow & 7);
        ps[qr][sidx] = f2bf(pa);
      }
    }

    const bf16x8 a0 = *(const bf16x8*)&ps[qloc][swA0];
    const bf16x8 a1 = *(const bf16x8*)&ps[qloc][swA1];
#pragma unroll
    for (int ds = 0; ds < 8; ++ds) {
      const int d = ds * 16 + l15;
      const bf16x8 bv0 = *(const bf16x8*)&vs[d][(lg ^ (d & 7)) << 3];
      const bf16x8 bv1 = *(const bf16x8*)&vs[d][((lg + 4) ^ (d & 7)) << 3];
      oacc[ds] = __builtin_amdgcn_mfma_f32_16x16x32_bf16(a0, bv0, oacc[ds], 0, 0, 0);
      oacc[ds] = __builtin_amdgcn_mfma_f32_16x16x32_bf16(a1, bv1, oacc[ds], 0, 0, 0);
    }
    __syncthreads();
  }

  // ---------- epilogue ----------
#pragma unroll
  for (int r = 0; r < 4; ++r)
#pragma unroll
    for (int off = 1; off < 16; off <<= 1)
      rs[r] += __shfl_xor(rs[r], off);

  const int b = bh >> 5, h = bh & 31;
#pragma unroll
  for (int r = 0; r < 4; ++r) {
    const float inv = 1.0f / (127.0f * rs[r]);
    float* op = attn + ((size_t)(b * S_LEN + qg[r])) * HDIM + h * DHEAD + l15;
#pragma unroll
    for (int ds = 0; ds < 8; ++ds)
      op[ds * 16] = oacc[ds][r] * inv;
  }
}

extern "C" void kernel_launch(void* const* d_in, const int* in_sizes, int n_in,
                              void* d_out, int out_size, void* d_ws, size_t ws_size,
                              hipStream_t stream) {
  const float* hs = (const float*)d_in[0];
  const float* wmat[4] = { (const float*)d_in[1], (const float*)d_in[2],
                           (const float*)d_in[3], (const float*)d_in[4] };

  char* p = (char*)d_ws;
  auto take = [&](size_t sz) { char* r = p; p += (sz + 255) & ~(size_t)255; return r; };

  int8_t* xq8 = (int8_t*)take((size_t)MTOK * HDIM);
  int8_t* w4[4];
  for (int i = 0; i < 4; ++i) w4[i] = (int8_t*)take((size_t)HDIM * HDIM);
  float* sx = (float*)take((size_t)MTOK * 4);
  float* sw[4];
  for (int i = 0; i < 4; ++i) sw[i] = (float*)take((size_t)HDIM * 4);
  float* y = (float*)take((size_t)MTOK * HDIM * 4);
  int8_t* qq8 = (int8_t*)take((size_t)MTOK * HDIM);
  int8_t* kq8 = (int8_t*)take((size_t)MTOK * HDIM);
  int8_t* vqT = (int8_t*)take((size_t)MTOK * HDIM);
  float* sqs = (float*)take((size_t)BATCH * NHEAD * S_LEN * 4);
  float* sks = (float*)take((size_t)BATCH * NHEAD * S_LEN * 4);
  float* svs = (float*)take((size_t)BATCH * NHEAD * S_LEN * 4);
  float* sattn = (float*)take((size_t)MTOK * 4);

  rowquant_kernel<<<MTOK, 256, 0, stream>>>(hs, xq8, sx, 127.f, -128.f);
  for (int i = 0; i < 4; ++i)
    rowquant_kernel<<<HDIM, 256, 0, stream>>>(wmat[i], w4[i], sw[i], 7.f, -8.f);

  const dim3 gg(HDIM / 128, MTOK / 128);  // (32,16) = 512 blocks
  gemm_i8_mfma_kernel<<<gg, 256, 0, stream>>>(xq8, sx, w4[0], sw[0], y);
  rope_quant_kernel<<<MTOK * NHEAD / 4, 256, 0, stream>>>(y, qq8, sqs, 1);
  gemm_i8_mfma_kernel<<<gg, 256, 0, stream>>>(xq8, sx, w4[1], sw[1], y);
  rope_quant_kernel<<<MTOK * NHEAD / 4, 256, 0, stream>>>(y, kq8, sks, 1);
  gemm_i8_mfma_kernel<<<gg, 256, 0, stream>>>(xq8, sx, w4[2], sw[2], y);
  vtrans_kernel<<<dim3(S_LEN / 64, BATCH * NHEAD), 256, 0, stream>>>(y, vqT, svs);

  attn_mfma_kernel<<<dim3(S_LEN / QB, BATCH * NHEAD), 256, 0, stream>>>(
      qq8, sqs, kq8, sks, vqT, svs, y);

  rowquant_kernel<<<MTOK, 256, 0, stream>>>(y, xq8, sattn, 127.f, -128.f);
  gemm_i8_mfma_kernel<<<gg, 256, 0, stream>>>(xq8, sattn, w4[3], sw[3], (float*)d_out);
}

// Round 4
// 417.550 us; speedup vs baseline: 7.5426x; 1.1853x over previous
//
#include <hip/hip_runtime.h>
#include <stdint.h>

#define S_LEN 1024
#define HDIM  4096
#define NHEAD 32
#define DHEAD 128
#define BATCH 2
#define MTOK  (BATCH * S_LEN)   // 2048

typedef __attribute__((ext_vector_type(4))) int   i32x4;
typedef __attribute__((ext_vector_type(4))) float f32x4;
typedef __attribute__((ext_vector_type(8))) short bf16x8;

#define GLOBAL_AS __attribute__((address_space(1)))
#define LDS_AS    __attribute__((address_space(3)))

__device__ __forceinline__ void gl2lds16(const void* g, void* l) {
  __builtin_amdgcn_global_load_lds((const GLOBAL_AS unsigned int*)(g),
                                   (LDS_AS unsigned int*)(l), 16, 0, 0);
}

// float -> bf16 bits, round-to-nearest-even (exact for small ints)
__device__ __forceinline__ unsigned short f2bf(float f) {
  unsigned int u = __float_as_uint(f);
  unsigned int r = (u + 0x7fffu + ((u >> 16) & 1u)) >> 16;
  return (unsigned short)r;
}

// -------- per-row symmetric fake-quant: x (row of 4096 f32) -> int8 + scale --------
__global__ __launch_bounds__(256) void rowquant_kernel(
    const float* __restrict__ x, int8_t* __restrict__ q,
    float* __restrict__ scales, float qmax, float clipLo)
{
  const int row = blockIdx.x;
  const int t = threadIdx.x;
  const float* xr = x + (size_t)row * HDIM;
  float4 v[4];
  float am = 0.f;
#pragma unroll
  for (int i = 0; i < 4; ++i) {
    v[i] = ((const float4*)xr)[t + 256 * i];
    am = fmaxf(am, fmaxf(fmaxf(fabsf(v[i].x), fabsf(v[i].y)),
                         fmaxf(fabsf(v[i].z), fabsf(v[i].w))));
  }
#pragma unroll
  for (int off = 32; off > 0; off >>= 1) am = fmaxf(am, __shfl_down(am, off));
  __shared__ float wred[4];
  if ((t & 63) == 0) wred[t >> 6] = am;
  __syncthreads();
  const float m = fmaxf(fmaxf(wred[0], wred[1]), fmaxf(wred[2], wred[3]));
  const float scale = fmaxf(m / qmax, 1e-8f);
  if (t == 0) scales[row] = scale;
  int* qo = (int*)(q + (size_t)row * HDIM);
#pragma unroll
  for (int i = 0; i < 4; ++i) {
    int b0 = (int)fminf(fmaxf(rintf(v[i].x / scale), clipLo), qmax);
    int b1 = (int)fminf(fmaxf(rintf(v[i].y / scale), clipLo), qmax);
    int b2 = (int)fminf(fmaxf(rintf(v[i].z / scale), clipLo), qmax);
    int b3 = (int)fminf(fmaxf(rintf(v[i].w / scale), clipLo), qmax);
    qo[t + 256 * i] = (b0 & 0xff) | ((b1 & 0xff) << 8) | ((b2 & 0xff) << 16) | ((b3 & 0xff) << 24);
  }
}

// -------- i8 MFMA GEMM: 128x128 tile, BK=128, 4 waves x 64x64 --------
__global__ __launch_bounds__(256) void gemm_i8_mfma_kernel(
    const int8_t* __restrict__ A, const float* __restrict__ sa,
    const int8_t* __restrict__ Bw, const float* __restrict__ sb,
    float* __restrict__ C)
{
  __shared__ __align__(16) int8_t asB[128 * 128];
  __shared__ __align__(16) int8_t bsB[128 * 128];

  const int flat = blockIdx.y * gridDim.x + blockIdx.x;
  const int nf = (flat & 7) * 64 + (flat >> 3);
  const int bx = nf & 31, by = nf >> 5;
  const int bm = by * 128, bn = bx * 128;

  const int tid = threadIdx.x;
  const int w = tid >> 6, l = tid & 63;
  const int l15 = l & 15, lg = l >> 4, l7 = l & 7;
  const int m0 = (w >> 1) * 64, n0 = (w & 1) * 64;

  const int lr = l >> 3;
  const int srcSlot = (l & 7) ^ lr;
  const int8_t* aRow = A + (size_t)(bm + lr) * HDIM + srcSlot * 16;
  const int8_t* bRow = Bw + (size_t)(bn + lr) * HDIM + srcSlot * 16;

  i32x4 acc[4][4];
#pragma unroll
  for (int i = 0; i < 4; ++i)
#pragma unroll
    for (int j = 0; j < 4; ++j) acc[i][j] = (i32x4){0, 0, 0, 0};

  for (int k0 = 0; k0 < HDIM; k0 += 128) {
#pragma unroll
    for (int i = 0; i < 4; ++i) {
      const int r0 = w * 32 + i * 8;
      gl2lds16(aRow + (size_t)r0 * HDIM + k0, asB + r0 * 128);
      gl2lds16(bRow + (size_t)r0 * HDIM + k0, bsB + r0 * 128);
    }
    __syncthreads();
#pragma unroll
    for (int kk = 0; kk < 2; ++kk) {
      i32x4 aF[4], bF[4];
      const int slot = (((kk << 2) + lg) ^ l7) << 4;
#pragma unroll
      for (int i = 0; i < 4; ++i)
        aF[i] = *(const i32x4*)(asB + (m0 + i * 16 + l15) * 128 + slot);
#pragma unroll
      for (int j = 0; j < 4; ++j)
        bF[j] = *(const i32x4*)(bsB + (n0 + j * 16 + l15) * 128 + slot);
#pragma unroll
      for (int i = 0; i < 4; ++i)
#pragma unroll
        for (int j = 0; j < 4; ++j)
          acc[i][j] = __builtin_amdgcn_mfma_i32_16x16x64_i8(aF[i], bF[j], acc[i][j], 0, 0, 0);
    }
    __syncthreads();
  }

  float sbr[4];
#pragma unroll
  for (int j = 0; j < 4; ++j) sbr[j] = sb[bn + n0 + j * 16 + l15];
#pragma unroll
  for (int i = 0; i < 4; ++i) {
#pragma unroll
    for (int r = 0; r < 4; ++r) {
      const int m = bm + m0 + i * 16 + lg * 4 + r;
      const float sm = sa[m];
      float* cp = C + (size_t)m * HDIM + bn + n0 + l15;
#pragma unroll
      for (int j = 0; j < 4; ++j)
        cp[j * 16] = sm * sbr[j] * (float)acc[i][j][r];
    }
  }
}

// -------- RoPE + per-(b,s,h) fake-quant8 for Q,K; layout [bh][s][128] --------
__global__ __launch_bounds__(256) void rope_quant_kernel(
    const float* __restrict__ y, int8_t* __restrict__ o8,
    float* __restrict__ oscale, int doRope)
{
  const int gw = (blockIdx.x * 256 + threadIdx.x) >> 6;
  const int lane = threadIdx.x & 63;
  const int h = gw & (NHEAD - 1);
  const int tok = gw >> 5;
  const int s = tok & (S_LEN - 1);
  const float* yr = y + (size_t)tok * HDIM + h * DHEAD;
  float x0 = yr[lane], x1 = yr[lane + 64];
  float o0, o1;
  if (doRope) {
    const float e = (float)lane * (1.0f / 64.0f);
    const float inv = powf(10000.0f, -e);
    const float ang = (float)s * inv;
    float sn, c;
    sincosf(ang, &sn, &c);
    o0 = x0 * c - x1 * sn;
    o1 = x1 * c + x0 * sn;
  } else {
    o0 = x0; o1 = x1;
  }
  float am = fmaxf(fabsf(o0), fabsf(o1));
#pragma unroll
  for (int off = 32; off > 0; off >>= 1) am = fmaxf(am, __shfl_xor(am, off));
  const float scale = fmaxf(am / 127.0f, 1e-8f);
  const float q0 = fminf(fmaxf(rintf(o0 / scale), -128.f), 127.f);
  const float q1 = fminf(fmaxf(rintf(o1 / scale), -128.f), 127.f);
  const size_t orow = (size_t)((tok >> 10) * NHEAD + h) * S_LEN + s;
  int8_t* op = o8 + orow * DHEAD;
  op[lane] = (int8_t)(int)q0;
  op[lane + 64] = (int8_t)(int)q1;
  if (lane == 0) oscale[orow] = scale;
}

// -------- V: quant per (b,h,s) row, fold sv in, store TRANSPOSED bf16 [bh][d][s] --------
__global__ __launch_bounds__(256) void vtrans_kernel(
    const float* __restrict__ y, unsigned short* __restrict__ vqT)
{
  __shared__ unsigned short vt[128][80];
  const int tid = threadIdx.x;
  const int wv = tid >> 6, lane = tid & 63;
  const int bh = blockIdx.y, s0 = blockIdx.x * 64;
  const int b = bh >> 5, h = bh & 31;
  for (int it = 0; it < 16; ++it) {
    const int tl = wv * 16 + it;
    const float* yr = y + ((size_t)(b * S_LEN + s0 + tl)) * HDIM + h * DHEAD;
    float x0 = yr[lane], x1 = yr[lane + 64];
    float am = fmaxf(fabsf(x0), fabsf(x1));
#pragma unroll
    for (int off = 32; off > 0; off >>= 1) am = fmaxf(am, __shfl_xor(am, off));
    const float scale = fmaxf(am / 127.0f, 1e-8f);
    const float q0 = fminf(fmaxf(rintf(x0 / scale), -128.f), 127.f);
    const float q1 = fminf(fmaxf(rintf(x1 / scale), -128.f), 127.f);
    vt[lane][tl] = f2bf(q0 * scale);      // sv folded into V (bf16)
    vt[lane + 64][tl] = f2bf(q1 * scale);
  }
  __syncthreads();
  const int d = tid >> 1, half = tid & 1;
  unsigned short* op = vqT + ((size_t)bh * 128 + d) * S_LEN + s0 + half * 32;
#pragma unroll
  for (int c = 0; c < 4; ++c)
    *(i32x4*)(op + c * 8) = *(const i32x4*)(&vt[d][half * 32 + c * 8]);
}

// -------- MFMA flash attention, causal-balanced: block does q-tiles (bx, 15-bx) --------
#define QB 64
#define KB 64

__global__ __launch_bounds__(256) void attn_mfma_kernel(
    const int8_t* __restrict__ qq, const float* __restrict__ sq,
    const int8_t* __restrict__ kq, const float* __restrict__ sk,
    const unsigned short* __restrict__ vqT,   // bf16 bits, sv pre-folded
    float* __restrict__ attn)
{
  __shared__ __align__(16) int8_t ks[KB * 128];
  __shared__ __align__(16) unsigned short vs[128 * 64];
  __shared__ __align__(16) unsigned short ps[QB][64];
  __shared__ float sk_t[KB];

  const int tid = threadIdx.x;
  const int w = tid >> 6;
  const int l = tid & 63;
  const int l15 = l & 15;
  const int lg = l >> 4;
  const int lr = l >> 3, g7 = l & 7;
  const int bh = blockIdx.y;
  const size_t bhS = (size_t)bh * S_LEN;
  const int b = bh >> 5, h = bh & 31;
  const int NT = S_LEN / QB;   // 16

  for (int rep = 0; rep < 2; ++rep) {
    const int qt = rep ? (NT - 1 - (int)blockIdx.x) : (int)blockIdx.x;
    const int q0 = qt * QB;
    const int nkt = qt + 1;

    const int qrow = q0 + w * 16 + l15;
    const int8_t* qp = qq + (bhS + qrow) * (size_t)DHEAD;
    const i32x4 qa0 = *(const i32x4*)(qp + lg * 16);
    const i32x4 qa1 = *(const i32x4*)(qp + 64 + lg * 16);

    float sqv[4];
    int qg[4];
#pragma unroll
    for (int r = 0; r < 4; ++r) {
      qg[r] = q0 + w * 16 + lg * 4 + r;
      // fold rsqrt(D) and log2(e): scores in log2 domain
      sqv[r] = sq[bhS + qg[r]] * 0.08838834764831843f * 1.4426950408889634f;
    }

    float rmax[4] = {-3.0e38f, -3.0e38f, -3.0e38f, -3.0e38f};

    // ---------- pass 1: exact row max (log2 domain) ----------
    for (int kt = 0; kt < nkt; ++kt) {
      const int k0 = kt * KB;
#pragma unroll
      for (int i = 0; i < 2; ++i) {
        const int r0 = w * 16 + i * 8;
        gl2lds16(kq + (bhS + k0 + r0 + lr) * (size_t)128 + ((g7 ^ lr) << 4),
                 ks + r0 * 128);
      }
      if (tid < KB) sk_t[tid] = sk[bhS + k0 + tid];
      __syncthreads();
      const bool diag = (kt == nkt - 1);
#pragma unroll
      for (int c = 0; c < 4; ++c) {
        const int krow = c * 16 + l15;
        const i32x4 b0 = *(const i32x4*)(ks + krow * 128 + ((lg ^ (krow & 7)) << 4));
        const i32x4 b1 = *(const i32x4*)(ks + krow * 128 + (((lg + 4) ^ (krow & 7)) << 4));
        i32x4 acc = {0, 0, 0, 0};
        acc = __builtin_amdgcn_mfma_i32_16x16x64_i8(qa0, b0, acc, 0, 0, 0);
        acc = __builtin_amdgcn_mfma_i32_16x16x64_i8(qa1, b1, acc, 0, 0, 0);
        const float skv = sk_t[krow];
        const int kgl = k0 + krow;
#pragma unroll
        for (int r = 0; r < 4; ++r) {
          const float s = (float)acc[r] * sqv[r] * skv;
          if (!diag || (kgl <= qg[r])) rmax[r] = fmaxf(rmax[r], s);
        }
      }
      __syncthreads();
    }
#pragma unroll
    for (int r = 0; r < 4; ++r)
#pragma unroll
      for (int off = 1; off < 16; off <<= 1)
        rmax[r] = fmaxf(rmax[r], __shfl_xor(rmax[r], off));

    // ---------- pass 2: P quant + PV ----------
    float rs[4] = {0.f, 0.f, 0.f, 0.f};
    f32x4 oacc[8];
#pragma unroll
    for (int ds = 0; ds < 8; ++ds) oacc[ds] = (f32x4){0.f, 0.f, 0.f, 0.f};

    const int qloc = w * 16 + l15;
    const int swA0 = (lg ^ (qloc & 7)) << 3;
    const int swA1 = ((lg + 4) ^ (qloc & 7)) << 3;

    for (int kt = 0; kt < nkt; ++kt) {
      const int k0 = kt * KB;
#pragma unroll
      for (int i = 0; i < 2; ++i) {
        const int r0 = w * 16 + i * 8;
        gl2lds16(kq + (bhS + k0 + r0 + lr) * (size_t)128 + ((g7 ^ lr) << 4),
                 ks + r0 * 128);
      }
#pragma unroll
      for (int i = 0; i < 4; ++i) {
        const int r0 = w * 32 + i * 8;
        const unsigned short* src = vqT + ((size_t)bh * 128 + r0 + lr) * S_LEN
                                        + k0 + ((g7 ^ lr) << 3);
        gl2lds16(src, vs + r0 * 64);
      }
      if (tid < KB) sk_t[tid] = sk[bhS + k0 + tid];
      __syncthreads();
      const bool diag = (kt == nkt - 1);

#pragma unroll
      for (int c = 0; c < 4; ++c) {
        const int krow = c * 16 + l15;
        const i32x4 b0 = *(const i32x4*)(ks + krow * 128 + ((lg ^ (krow & 7)) << 4));
        const i32x4 b1 = *(const i32x4*)(ks + krow * 128 + (((lg + 4) ^ (krow & 7)) << 4));
        i32x4 acc = {0, 0, 0, 0};
        acc = __builtin_amdgcn_mfma_i32_16x16x64_i8(qa0, b0, acc, 0, 0, 0);
        acc = __builtin_amdgcn_mfma_i32_16x16x64_i8(qa1, b1, acc, 0, 0, 0);
        const float skv = sk_t[krow];
        const int kgl = k0 + krow;
#pragma unroll
        for (int r = 0; r < 4; ++r) {
          const float s2 = (float)acc[r] * sqv[r] * skv;
          const bool valid = !diag || (kgl <= qg[r]);
          const float e = valid ? exp2f(s2 - rmax[r]) : 0.0f;
          rs[r] += e;
          const float p = rintf(e * 127.0f);   // exact small int -> bf16 exact
          const int qr = w * 16 + lg * 4 + r;
          const int sidx = (((krow >> 3) ^ (qr & 7)) << 3) | (krow & 7);
          ps[qr][sidx] = f2bf(p);
        }
      }

      const bf16x8 a0 = *(const bf16x8*)&ps[qloc][swA0];
      const bf16x8 a1 = *(const bf16x8*)&ps[qloc][swA1];
#pragma unroll
      for (int ds = 0; ds < 8; ++ds) {
        const int d = ds * 16 + l15;
        const bf16x8 bv0 = *(const bf16x8*)(vs + d * 64 + ((lg ^ (d & 7)) << 3));
        const bf16x8 bv1 = *(const bf16x8*)(vs + d * 64 + (((lg + 4) ^ (d & 7)) << 3));
        oacc[ds] = __builtin_amdgcn_mfma_f32_16x16x32_bf16(a0, bv0, oacc[ds], 0, 0, 0);
        oacc[ds] = __builtin_amdgcn_mfma_f32_16x16x32_bf16(a1, bv1, oacc[ds], 0, 0, 0);
      }
      __syncthreads();
    }

    // ---------- epilogue ----------
#pragma unroll
    for (int r = 0; r < 4; ++r)
#pragma unroll
      for (int off = 1; off < 16; off <<= 1)
        rs[r] += __shfl_xor(rs[r], off);

#pragma unroll
    for (int r = 0; r < 4; ++r) {
      const float inv = 1.0f / (127.0f * rs[r]);
      float* op = attn + ((size_t)(b * S_LEN + qg[r])) * HDIM + h * DHEAD + l15;
#pragma unroll
      for (int ds = 0; ds < 8; ++ds)
        op[ds * 16] = oacc[ds][r] * inv;
    }
  }
}

extern "C" void kernel_launch(void* const* d_in, const int* in_sizes, int n_in,
                              void* d_out, int out_size, void* d_ws, size_t ws_size,
                              hipStream_t stream) {
  const float* hs = (const float*)d_in[0];
  const float* wmat[4] = { (const float*)d_in[1], (const float*)d_in[2],
                           (const float*)d_in[3], (const float*)d_in[4] };

  char* p = (char*)d_ws;
  auto take = [&](size_t sz) { char* r = p; p += (sz + 255) & ~(size_t)255; return r; };

  int8_t* xq8 = (int8_t*)take((size_t)MTOK * HDIM);
  int8_t* w4[4];
  for (int i = 0; i < 4; ++i) w4[i] = (int8_t*)take((size_t)HDIM * HDIM);
  float* sx = (float*)take((size_t)MTOK * 4);
  float* sw[4];
  for (int i = 0; i < 4; ++i) sw[i] = (float*)take((size_t)HDIM * 4);
  float* y = (float*)take((size_t)MTOK * HDIM * 4);
  int8_t* qq8 = (int8_t*)take((size_t)MTOK * HDIM);
  int8_t* kq8 = (int8_t*)take((size_t)MTOK * HDIM);
  unsigned short* vqT = (unsigned short*)take((size_t)MTOK * HDIM * 2);
  float* sqs = (float*)take((size_t)BATCH * NHEAD * S_LEN * 4);
  float* sks = (float*)take((size_t)BATCH * NHEAD * S_LEN * 4);
  float* sattn = (float*)take((size_t)MTOK * 4);

  rowquant_kernel<<<MTOK, 256, 0, stream>>>(hs, xq8, sx, 127.f, -128.f);
  for (int i = 0; i < 4; ++i)
    rowquant_kernel<<<HDIM, 256, 0, stream>>>(wmat[i], w4[i], sw[i], 7.f, -8.f);

  const dim3 gg(HDIM / 128, MTOK / 128);  // 512 blocks
  gemm_i8_mfma_kernel<<<gg, 256, 0, stream>>>(xq8, sx, w4[0], sw[0], y);
  rope_quant_kernel<<<MTOK * NHEAD / 4, 256, 0, stream>>>(y, qq8, sqs, 1);
  gemm_i8_mfma_kernel<<<gg, 256, 0, stream>>>(xq8, sx, w4[1], sw[1], y);
  rope_quant_kernel<<<MTOK * NHEAD / 4, 256, 0, stream>>>(y, kq8, sks, 1);
  gemm_i8_mfma_kernel<<<gg, 256, 0, stream>>>(xq8, sx, w4[2], sw[2], y);
  vtrans_kernel<<<dim3(S_LEN / 64, BATCH * NHEAD), 256, 0, stream>>>(y, vqT);

  attn_mfma_kernel<<<dim3(S_LEN / QB / 2, BATCH * NHEAD), 256, 0, stream>>>(
      qq8, sqs, kq8, sks, vqT, y);

  rowquant_kernel<<<MTOK, 256, 0, stream>>>(y, xq8, sattn, 127.f, -128.f);
  gemm_i8_mfma_kernel<<<gg, 256, 0, stream>>>(xq8, sattn, w4[3], sw[3], (float*)d_out);
}